// Round 3
// baseline (679.107 us; speedup 1.0000x reference)
//
#include <hip/hip_runtime.h>

typedef __attribute__((ext_vector_type(4))) float f32x4;
typedef __attribute__((ext_vector_type(8))) short s16x8;

#define DEV static __device__ __forceinline__

constexpr int Tn = 256, Bn = 1024, Sn = 8, Dn = 32, On = 4;

struct Params {
  const float* obs; const float* enc_w; const float* enc_b;
  const float* mw[15];            // wW wI wA zW zI zA rW rI rA hW hI hA aW aI aA
  const float* gw[4];             // att wmg img amg  [32 x 64]
  const float* gb[4];
  const float* z_b; const float* r_b; const float* h_b; const float* a_b;
  const float* phi_w; const float* phi_b;
  float* out;
};

DEV unsigned short f2bf(float x) {
  unsigned int u = __float_as_uint(x);
  u += 0x7fffu + ((u >> 16) & 1u);           // round-to-nearest-even
  return (unsigned short)(u >> 16);
}

DEV f32x4 ld4(const float* p) { return *(const f32x4*)p; }

DEV s16x8 pack8(f32x4 a, f32x4 b) {
  s16x8 r;
  r[0]=(short)f2bf(a[0]); r[1]=(short)f2bf(a[1]); r[2]=(short)f2bf(a[2]); r[3]=(short)f2bf(a[3]);
  r[4]=(short)f2bf(b[0]); r[5]=(short)f2bf(b[1]); r[6]=(short)f2bf(b[2]); r[7]=(short)f2bf(b[3]);
  return r;
}

DEV s16x8 zero8() { s16x8 r = {0,0,0,0,0,0,0,0}; return r; }

// B-fragment: lane holds w[row][col0 .. col0+7] (k = 8*(lane>>4)+e convention,
// consistent on A and B sides => k-permutation invariant, always correct)
DEV s16x8 load_bfrag(const float* w, int row, int ldk, int col0) {
  const float* p = w + row*ldk + col0;
  return pack8(ld4(p), ld4(p+4));
}

DEV f32x4 MF(s16x8 a, s16x8 b, f32x4 c) {
  return __builtin_amdgcn_mfma_f32_16x16x32_bf16(a, b, c, 0, 0, 0);
}

DEV f32x4 splat4(float v) { f32x4 r = {v,v,v,v}; return r; }

DEV float rcpf_(float x) { return __builtin_amdgcn_rcpf(x); }
DEV float sigm(float x)  { return rcpf_(1.f + __expf(-x)); }
DEV float tanh_(float x) { return 2.f * rcpf_(1.f + __expf(-2.f*x)) - 1.f; }

DEV s16x8 cvt8(const float* v) {
  s16x8 r;
#pragma unroll
  for (int e = 0; e < 8; ++e) r[e] = (short)f2bf(v[e]);
  return r;
}

// D-layout (col=lane&15, row=4*(lane>>4)+reg, m89-verified) -> LDS [16][36] padded
DEV void wrv(float* lds, int h, int c, int v, f32x4 a0, f32x4 a1) {
  float* base = lds + v*576;
#pragma unroll
  for (int rr = 0; rr < 4; ++rr) {
    int row = 4*h + rr;
    base[row*36 + c]      = a0[rr];
    base[row*36 + 16 + c] = a1[rr];
  }
}
// read back in A-layout: lane gets batch-row (lane&15), k = 8*(lane>>4)+e
DEV void rdv(const float* lds, int h, int c, int v, float* o) {
  const f32x4* p = (const f32x4*)(lds + v*576 + c*36 + 8*h);
  f32x4 a = p[0], b = p[1];
#pragma unroll
  for (int e = 0; e < 4; ++e) { o[e] = a[e]; o[4+e] = b[e]; }
}

__global__ __launch_bounds__(64, 1) void anima_kernel(Params P) {
  const int lane = threadIdx.x;
  const int h = lane >> 4, c = lane & 15;
  const int bbase = blockIdx.x * 16;

  __shared__ __align__(16) float lds[4*16*36];

  // ---- persistent weight fragments (loaded from HBM exactly once) ----
  s16x8 m[15][2];
#pragma unroll
  for (int i = 0; i < 15; ++i)
#pragma unroll
    for (int j = 0; j < 2; ++j)
      m[i][j] = load_bfrag(P.mw[i], j*16 + c, 32, 8*h);

  s16x8 g[4][2][2];   // [gate][k-chunk][d-half]
#pragma unroll
  for (int i = 0; i < 4; ++i)
#pragma unroll
    for (int q = 0; q < 2; ++q)
#pragma unroll
      for (int j = 0; j < 2; ++j)
        g[i][q][j] = load_bfrag(P.gw[i], j*16 + c, 64, 32*q + 8*h);

  s16x8 ef[2];        // encoder, K padded 8->32 with zeros (consistent on A side)
#pragma unroll
  for (int j = 0; j < 2; ++j)
    ef[j] = (h == 0) ? load_bfrag(P.enc_w, j*16 + c, 8, 0) : zero8();

  s16x8 pf = (c < 4) ? load_bfrag(P.phi_w, c, 32, 8*h) : zero8();  // N padded 4->16

  float bEnc[2], bAtt[2], bWmg[2], bImg[2], bAmg[2], bZ[2], bR[2], bH[2], bA[2];
#pragma unroll
  for (int j = 0; j < 2; ++j) {
    int d = j*16 + c;
    bEnc[j] = P.enc_b[d]; bAtt[j] = P.gb[0][d]; bWmg[j] = P.gb[1][d];
    bImg[j] = P.gb[2][d]; bAmg[j] = P.gb[3][d];
    bZ[j] = P.z_b[d]; bR[j] = P.r_b[d]; bH[j] = P.h_b[d]; bA[j] = P.a_b[d];
  }
  const float pbias = (c < 4) ? P.phi_b[c] : 0.f;

  // ---- state: I in fp32 (A-layout), W/I/A as bf16 A-frags ----
  float iv[8];
#pragma unroll
  for (int e = 0; e < 8; ++e) iv[e] = 0.f;
  s16x8 Wf = zero8(), If = zero8(), Af = zero8();

  f32x4 ob0 = splat4(0.f), ob1 = splat4(0.f);
  if (h == 0) {
    const float* p = P.obs + (size_t)(bbase + c) * Sn;
    ob0 = ld4(p); ob1 = ld4(p + 4);
  }

#pragma unroll 1
  for (int t = 0; t < Tn; ++t) {
    s16x8 Of = zero8();
    if (h == 0) Of = pack8(ob0, ob1);
    f32x4 nb0 = ob0, nb1 = ob1;
    if (h == 0 && t + 1 < Tn) {            // prefetch next step's obs
      const float* p = P.obs + ((size_t)(t + 1) * Bn + bbase + c) * Sn;
      nb0 = ld4(p); nb1 = ld4(p + 4);
    }

    // ---- phase A: W_all, attn_pre, mult_pre, enc_pre ----
    f32x4 aWl[2], aAt[2], aMu[2], aE[2];
#pragma unroll
    for (int j = 0; j < 2; ++j) {
      f32x4 x = MF(Wf, m[0][j], splat4(0.f));
      x = MF(If, m[1][j], x);
      aWl[j] = MF(Af, m[2][j], x);
      f32x4 y = MF(Wf, g[0][0][j], splat4(bAtt[j]));   // att over [W, I]
      aAt[j] = MF(If, g[0][1][j], y);
      f32x4 u = MF(If, g[1][0][j], splat4(bWmg[j]));   // wmg over [I, A]
      aMu[j] = MF(Af, g[1][1][j], u);
      aE[j]  = MF(Of, ef[j], splat4(bEnc[j]));
    }
    wrv(lds, h, c, 0, aWl[0], aWl[1]); wrv(lds, h, c, 1, aAt[0], aAt[1]);
    wrv(lds, h, c, 2, aMu[0], aMu[1]); wrv(lds, h, c, 3, aE[0], aE[1]);
    float wall[8], att[8], mul[8], enc[8];
    rdv(lds, h, c, 0, wall); rdv(lds, h, c, 1, att);
    rdv(lds, h, c, 2, mul);  rdv(lds, h, c, 3, enc);
    float wn[8];
#pragma unroll
    for (int e = 0; e < 8; ++e) {
      float at = sigm(att[e]);
      float mu = sigm(mul[e]);
      float oe = tanh_(enc[e]);
      wn[e] = tanh_(oe * at + wall[e] * mu);
    }
    s16x8 Wnf = cvt8(wn);

    // ---- phase B: z, r, mult_I ----
    f32x4 aZ[2], aR[2], aMI[2];
#pragma unroll
    for (int j = 0; j < 2; ++j) {
      f32x4 x = MF(Wnf, m[3][j], splat4(bZ[j]));
      x = MF(If, m[4][j], x);
      aZ[j] = MF(Af, m[5][j], x);
      f32x4 y = MF(Wnf, m[6][j], splat4(bR[j]));
      y = MF(If, m[7][j], y);
      aR[j] = MF(Af, m[8][j], y);
      f32x4 u = MF(Wnf, g[2][0][j], splat4(bImg[j]));  // img over [W_new, A]
      aMI[j] = MF(Af, g[2][1][j], u);
    }
    wrv(lds, h, c, 0, aZ[0], aZ[1]); wrv(lds, h, c, 1, aR[0], aR[1]);
    wrv(lds, h, c, 2, aMI[0], aMI[1]);
    float z8[8], r8[8], mi8[8];
    rdv(lds, h, c, 0, z8); rdv(lds, h, c, 1, r8); rdv(lds, h, c, 2, mi8);
    float zz[8], ri[8], miv[8];
#pragma unroll
    for (int e = 0; e < 8; ++e) {
      zz[e]  = sigm(z8[e]);
      ri[e]  = sigm(r8[e]) * iv[e];
      miv[e] = sigm(mi8[e]);
    }
    s16x8 rIf = cvt8(ri);

    // ---- phase C: h, I_new ----
    f32x4 aH[2];
#pragma unroll
    for (int j = 0; j < 2; ++j) {
      f32x4 x = MF(Wnf, m[9][j], splat4(bH[j]));
      x = MF(rIf, m[10][j], x);
      aH[j] = MF(Af, m[11][j], x);
    }
    wrv(lds, h, c, 0, aH[0], aH[1]);
    float h8[8];
    rdv(lds, h, c, 0, h8);
    float inew[8];
#pragma unroll
    for (int e = 0; e < 8; ++e) {
      float hv = tanh_(h8[e]);
      inew[e] = (1.f - zz[e]) * iv[e] + zz[e] * hv * miv[e];
    }
    s16x8 Inf = cvt8(inew);

    // ---- phase D: A_all, mult_A, A_new ----
    f32x4 aAl[2], aMA[2];
#pragma unroll
    for (int j = 0; j < 2; ++j) {
      f32x4 x = MF(Wnf, m[12][j], splat4(bA[j]));
      x = MF(Inf, m[13][j], x);
      aAl[j] = MF(Af, m[14][j], x);
      f32x4 y = MF(Wnf, g[3][0][j], splat4(bAmg[j]));  // amg over [W_new, I_new]
      aMA[j] = MF(Inf, g[3][1][j], y);
    }
    wrv(lds, h, c, 0, aAl[0], aAl[1]); wrv(lds, h, c, 1, aMA[0], aMA[1]);
    float aall[8], ma8[8];
    rdv(lds, h, c, 0, aall); rdv(lds, h, c, 1, ma8);
    float an[8];
#pragma unroll
    for (int e = 0; e < 8; ++e)
      an[e] = tanh_(aall[e] * sigm(ma8[e]));
    s16x8 Anf = cvt8(an);

    // ---- phase E: action = phi(A_new) + phi_b ----
    f32x4 aP = MF(Anf, pf, splat4(pbias));
    if (c < 4) {
#pragma unroll
      for (int rr = 0; rr < 4; ++rr)
        P.out[((size_t)t * Bn + bbase + 4*h + rr) * On + c] = aP[rr];
    }

    // ---- rotate state ----
    Wf = Wnf; If = Inf; Af = Anf;
#pragma unroll
    for (int e = 0; e < 8; ++e) iv[e] = inew[e];
    ob0 = nb0; ob1 = nb1;
  }
}

extern "C" void kernel_launch(void* const* d_in, const int* in_sizes, int n_in,
                              void* d_out, int out_size, void* d_ws, size_t ws_size,
                              hipStream_t stream) {
  (void)in_sizes; (void)n_in; (void)d_ws; (void)ws_size; (void)out_size;
  Params p;
  p.obs   = (const float*)d_in[0];
  p.enc_w = (const float*)d_in[1];
  p.enc_b = (const float*)d_in[2];
  for (int i = 0; i < 15; ++i) p.mw[i] = (const float*)d_in[3 + i];
  for (int i = 0; i < 4; ++i) {
    p.gw[i] = (const float*)d_in[18 + 2*i];
    p.gb[i] = (const float*)d_in[19 + 2*i];
  }
  p.z_b   = (const float*)d_in[26];
  p.r_b   = (const float*)d_in[27];
  p.h_b   = (const float*)d_in[28];
  p.a_b   = (const float*)d_in[29];
  p.phi_w = (const float*)d_in[30];
  p.phi_b = (const float*)d_in[31];
  p.out   = (float*)d_out;

  hipLaunchKernelGGL(anima_kernel, dim3(Bn / 16), dim3(64), 0, stream, p);
}

// Round 5
// 556.736 us; speedup vs baseline: 1.2198x; 1.2198x over previous
//
#include <hip/hip_runtime.h>

typedef __attribute__((ext_vector_type(4))) float f32x4;
typedef __attribute__((ext_vector_type(8))) short s16x8;

#define DEV static __device__ __forceinline__

constexpr int Tn = 256, Bn = 1024, Sn = 8;

struct Params {
  const float* obs; const float* enc_w; const float* enc_b;
  const float* mw[15];            // wW wI wA zW zI zA rW rI rA hW hI hA aW aI aA
  const float* gw[4];             // att wmg img amg  [32 x 64]
  const float* gb[4];
  const float* z_b; const float* r_b; const float* h_b; const float* a_b;
  const float* phi_w; const float* phi_b;
  float* out;
};

DEV unsigned short f2bf(float x) {
  unsigned int u = __float_as_uint(x);
  u += 0x7fffu + ((u >> 16) & 1u);           // round-to-nearest-even
  return (unsigned short)(u >> 16);
}

DEV f32x4 ld4(const float* p) { return *(const f32x4*)p; }
DEV f32x4 zero4() { f32x4 r = {0.f,0.f,0.f,0.f}; return r; }
DEV s16x8 zero8() { s16x8 r = {0,0,0,0,0,0,0,0}; return r; }

// pack two f32x4 (j=0 block, j=1 block) into a bf16x8 fragment.
// elem e=0..3 <-> k = 4h+e ; e=4..7 <-> k = 16+4h+(e-4)   [k-map lambda]
DEV s16x8 pk2(f32x4 a, f32x4 b) {
  s16x8 r;
  r[0]=(short)f2bf(a[0]); r[1]=(short)f2bf(a[1]); r[2]=(short)f2bf(a[2]); r[3]=(short)f2bf(a[3]);
  r[4]=(short)f2bf(b[0]); r[5]=(short)f2bf(b[1]); r[6]=(short)f2bf(b[2]); r[7]=(short)f2bf(b[3]);
  return r;
}

// weight fragment (A-operand of swapped MFMA): lane (h,c) holds
// row (=outdim) index c, k-cols {kofs+4h..+3, kofs+16+4h..+3} per lambda.
DEV s16x8 wfrag(const float* w, int row, int ldk, int kofs, int h) {
  const float* p = w + row*ldk + kofs + 4*h;
  return pk2(ld4(p), ld4(p+16));
}

DEV f32x4 MF(s16x8 a, s16x8 b, f32x4 c) {
  return __builtin_amdgcn_mfma_f32_16x16x32_bf16(a, b, c, 0, 0, 0);
}

DEV float sigm(float x)  {   // 1/(1+2^(-x*log2e)) : mul, exp2, add, rcp
  return __builtin_amdgcn_rcpf(1.f + __builtin_amdgcn_exp2f(x * -1.44269504f));
}
DEV float tanh_(float x) {   // 1 - 2/(2^(x*2log2e)+1)
  return 1.f - 2.f*__builtin_amdgcn_rcpf(1.f + __builtin_amdgcn_exp2f(x * 2.88539008f));
}

__global__ __launch_bounds__(64, 1) void anima_kernel(Params P) {
  const int lane = threadIdx.x;
  const int h = lane >> 4, c = lane & 15;
  const int bbase = blockIdx.x * 16;

  // ---- persistent weight fragments (HBM exactly once), swapped-A layout ----
  s16x8 m[15][2];
#pragma unroll
  for (int i = 0; i < 15; ++i)
#pragma unroll
    for (int j = 0; j < 2; ++j)
      m[i][j] = wfrag(P.mw[i], j*16 + c, 32, 0, h);

  s16x8 g[4][2][2];   // [gate][k-chunk q][out-block j]
#pragma unroll
  for (int i = 0; i < 4; ++i)
#pragma unroll
    for (int q = 0; q < 2; ++q)
#pragma unroll
      for (int j = 0; j < 2; ++j)
        g[i][q][j] = wfrag(P.gw[i], j*16 + c, 64, 32*q, h);

  s16x8 ef[2];        // encoder [32x8]: k valid only 0..7 -> h=0 (k0..3), h=1 (k4..7)
#pragma unroll
  for (int j = 0; j < 2; ++j) {
    if (h < 2) { f32x4 v = ld4(P.enc_w + (j*16 + c)*Sn + 4*h); ef[j] = pk2(v, zero4()); }
    else ef[j] = zero8();
  }

  s16x8 pf = (c < 4) ? wfrag(P.phi_w, c, 32, 0, h) : zero8();  // phi [4x32], M padded

  // ---- bias accumulator-init vectors: index = outdim 16j+4h+r ----
  f32x4 bE[2],bAt[2],bMu[2],bMI[2],bMA[2],bZ[2],bR[2],bH[2],bA[2];
#pragma unroll
  for (int j = 0; j < 2; ++j) {
    int o = j*16 + 4*h;
    bE[j]  = ld4(P.enc_b + o);  bAt[j] = ld4(P.gb[0] + o); bMu[j] = ld4(P.gb[1] + o);
    bMI[j] = ld4(P.gb[2] + o);  bMA[j] = ld4(P.gb[3] + o);
    bZ[j]  = ld4(P.z_b + o);    bR[j]  = ld4(P.r_b + o);
    bH[j]  = ld4(P.h_b + o);    bA[j]  = ld4(P.a_b + o);
  }
  f32x4 pb = (h == 0) ? ld4(P.phi_b) : zero4();

  // ---- state: lane (h,c) holds batch-row c, dims {4h+r, 16+4h+r} ----
  f32x4 iv[2] = { zero4(), zero4() };            // I in fp32
  s16x8 Wf = zero8(), If = zero8(), Af = zero8();

  f32x4 ob = zero4();
  if (h < 2) ob = ld4(P.obs + (size_t)(bbase + c) * Sn + 4*h);

#pragma unroll 1
  for (int t = 0; t < Tn; ++t) {
    s16x8 Of = (h < 2) ? pk2(ob, zero4()) : zero8();
    f32x4 nb = ob;
    if (h < 2 && t + 1 < Tn)                      // prefetch next obs
      nb = ld4(P.obs + ((size_t)(t + 1) * Bn + bbase + c) * Sn + 4*h);

    // ---- phase A: W_all, attn, wmg, enc (all swapped: D^T[outdim][batch]) ----
    f32x4 aWl[2], aAt[2], aMu[2], aE[2];
#pragma unroll
    for (int j = 0; j < 2; ++j) {
      f32x4 x = MF(m[0][j], Wf, zero4());
      x = MF(m[1][j], If, x);
      aWl[j] = MF(m[2][j], Af, x);
      f32x4 y = MF(g[0][0][j], Wf, bAt[j]);      // att over [W, I]
      aAt[j] = MF(g[0][1][j], If, y);
      f32x4 u = MF(g[1][0][j], If, bMu[j]);      // wmg over [I, A]
      aMu[j] = MF(g[1][1][j], Af, u);
      aE[j]  = MF(ef[j], Of, bE[j]);
    }
    f32x4 wn[2];
#pragma unroll
    for (int j = 0; j < 2; ++j)
#pragma unroll
      for (int r = 0; r < 4; ++r)
        wn[j][r] = tanh_( tanh_(aE[j][r]) * sigm(aAt[j][r]) + aWl[j][r] * sigm(aMu[j][r]) );
    s16x8 Wnf = pk2(wn[0], wn[1]);

    // ---- phase B: z, r, mult_I ----
    f32x4 aZ[2], aR[2], aMI[2];
#pragma unroll
    for (int j = 0; j < 2; ++j) {
      f32x4 x = MF(m[3][j], Wnf, bZ[j]);
      x = MF(m[4][j], If, x);
      aZ[j] = MF(m[5][j], Af, x);
      f32x4 y = MF(m[6][j], Wnf, bR[j]);
      y = MF(m[7][j], If, y);
      aR[j] = MF(m[8][j], Af, y);
      f32x4 u = MF(g[2][0][j], Wnf, bMI[j]);     // img over [W_new, A]
      aMI[j] = MF(g[2][1][j], Af, u);
    }
    f32x4 zz[2], ri[2], mi[2];
#pragma unroll
    for (int j = 0; j < 2; ++j)
#pragma unroll
      for (int r = 0; r < 4; ++r) {
        zz[j][r] = sigm(aZ[j][r]);
        ri[j][r] = sigm(aR[j][r]) * iv[j][r];
        mi[j][r] = sigm(aMI[j][r]);
      }
    s16x8 rIf = pk2(ri[0], ri[1]);

    // ---- phase C: h, I_new ----
    f32x4 aH[2];
#pragma unroll
    for (int j = 0; j < 2; ++j) {
      f32x4 x = MF(m[9][j], Wnf, bH[j]);
      x = MF(m[10][j], rIf, x);
      aH[j] = MF(m[11][j], Af, x);
    }
    f32x4 inw[2];
#pragma unroll
    for (int j = 0; j < 2; ++j)
#pragma unroll
      for (int r = 0; r < 4; ++r)
        inw[j][r] = (1.f - zz[j][r]) * iv[j][r] + zz[j][r] * tanh_(aH[j][r]) * mi[j][r];
    s16x8 Inf = pk2(inw[0], inw[1]);

    // ---- phase D: A_all, mult_A, A_new ----
    f32x4 aAl[2], aMA[2];
#pragma unroll
    for (int j = 0; j < 2; ++j) {
      f32x4 x = MF(m[12][j], Wnf, bA[j]);
      x = MF(m[13][j], Inf, x);
      aAl[j] = MF(m[14][j], Af, x);
      f32x4 y = MF(g[3][0][j], Wnf, bMA[j]);     // amg over [W_new, I_new]
      aMA[j] = MF(g[3][1][j], Inf, y);
    }
    f32x4 an[2];
#pragma unroll
    for (int j = 0; j < 2; ++j)
#pragma unroll
      for (int r = 0; r < 4; ++r)
        an[j][r] = tanh_(aAl[j][r] * sigm(aMA[j][r]));
    s16x8 Anf = pk2(an[0], an[1]);

    // ---- phase E: action = phi(A_new) + phi_b : h=0 lane holds out[c][0..4) ----
    f32x4 aP = MF(pf, Anf, pb);
    if (h == 0)
      *(f32x4*)(P.out + ((size_t)t * Bn + bbase + c) * 4) = aP;

    // ---- rotate state ----
    Wf = Wnf; If = Inf; Af = Anf;
    iv[0] = inw[0]; iv[1] = inw[1];
    ob = nb;
  }
}

extern "C" void kernel_launch(void* const* d_in, const int* in_sizes, int n_in,
                              void* d_out, int out_size, void* d_ws, size_t ws_size,
                              hipStream_t stream) {
  (void)in_sizes; (void)n_in; (void)d_ws; (void)ws_size; (void)out_size;
  Params p;
  p.obs   = (const float*)d_in[0];
  p.enc_w = (const float*)d_in[1];
  p.enc_b = (const float*)d_in[2];
  for (int i = 0; i < 15; ++i) p.mw[i] = (const float*)d_in[3 + i];
  for (int i = 0; i < 4; ++i) {
    p.gw[i] = (const float*)d_in[18 + 2*i];
    p.gb[i] = (const float*)d_in[19 + 2*i];
  }
  p.z_b   = (const float*)d_in[26];
  p.r_b   = (const float*)d_in[27];
  p.h_b   = (const float*)d_in[28];
  p.a_b   = (const float*)d_in[29];
  p.phi_w = (const float*)d_in[30];
  p.phi_b = (const float*)d_in[31];
  p.out   = (float*)d_out;

  hipLaunchKernelGGL(anima_kernel, dim3(Bn / 16), dim3(64), 0, stream, p);
}

// Round 8
// 412.322 us; speedup vs baseline: 1.6470x; 1.3502x over previous
//
#include <hip/hip_runtime.h>
#include <hip/hip_bf16.h>

typedef __attribute__((ext_vector_type(4))) float f32x4;
typedef __attribute__((ext_vector_type(8))) short s16x8;
typedef __attribute__((ext_vector_type(2))) unsigned int u32x2;
typedef __attribute__((ext_vector_type(4))) unsigned int u32x4;

#define DEV static __device__ __forceinline__

constexpr int Tn = 256, Bn = 1024, Sn = 8;
constexpr float L2E   =  1.44269504f;
constexpr float NL2E  = -1.44269504f;   // fold into sigmoid-arg weights
constexpr float N2L2E = -2.88539008f;   // fold into tanh-arg weights

struct Params {
  const float* obs; const float* enc_w; const float* enc_b;
  const float* mw[15];            // wW wI wA zW zI zA rW rI rA hW hI hA aW aI aA
  const float* gw[4];             // att wmg img amg  [32 x 64]
  const float* gb[4];
  const float* z_b; const float* r_b; const float* h_b; const float* a_b;
  const float* phi_w; const float* phi_b;
  float* out;
};

DEV f32x4 ld4(const float* p) { return *(const f32x4*)p; }
DEV f32x4 zero4() { f32x4 r = {0.f,0.f,0.f,0.f}; return r; }
DEV s16x8 zero8() { s16x8 r = {0,0,0,0,0,0,0,0}; return r; }

// packed f32->bf16 pair (RNE) -> v_cvt_pk_bf16_f32
DEV unsigned cvtpk(float a, float b) {
  __hip_bfloat162 t = __float22bfloat162_rn(make_float2(a, b));
  unsigned u; __builtin_memcpy(&u, &t, 4);
  return u;
}

// pack 8 scaled f32 into a bf16x8 fragment; elem e=0..3 <-> k=4h+e,
// e=4..7 <-> k=16+4h+(e-4)  [same k-map lambda on A and B sides]
DEV s16x8 pk2s(f32x4 a, f32x4 b, float s) {
  u32x4 f;
  f[0] = cvtpk(a[0]*s, a[1]*s); f[1] = cvtpk(a[2]*s, a[3]*s);
  f[2] = cvtpk(b[0]*s, b[1]*s); f[3] = cvtpk(b[2]*s, b[3]*s);
  s16x8 r; __builtin_memcpy(&r, &f, 16);
  return r;
}

// weight fragment (A-operand of swapped MFMA): lane (h,c) holds matrix row
// `row`, k-cols {kofs+4h..+3, kofs+16+4h..+3}; values pre-scaled by s.
DEV s16x8 wfrag(const float* w, int row, int ldk, int kofs, int h, float s) {
  const float* p = w + row*ldk + kofs + 4*h;
  return pk2s(ld4(p), ld4(p+16), s);
}

DEV f32x4 MF(s16x8 a, s16x8 b, f32x4 c) {
  return __builtin_amdgcn_mfma_f32_16x16x32_bf16(a, b, c, 0, 0, 0);
}

DEV float ex2(float x)  { return __builtin_amdgcn_exp2f(x); }
DEV float rcp_(float x) { return __builtin_amdgcn_rcpf(x); }
// activations with the scale already folded into the argument:
DEV float sg(float a) { return rcp_(1.f + ex2(a)); }                 // sigmoid(x), a=-L2E*x
DEV float th(float a) { return fmaf(rcp_(1.f + ex2(a)), 2.f, -1.f); } // tanh(x), a=-2L2E*x

DEV unsigned long long pack64(u32x2 v) {
  return ((unsigned long long)v[1] << 32) | v[0];
}
DEV u32x2 unpack64(unsigned long long x) {
  u32x2 r; r[0] = (unsigned)x; r[1] = (unsigned)(x >> 32); return r;
}
DEV u32x2 pkx(f32x4 v) {
  u32x2 r; r[0] = cvtpk(v[0], v[1]); r[1] = cvtpk(v[2], v[3]); return r;
}
// assemble full 32-k state fragment from own half + partner half
DEV s16x8 frag(u32x2 own, u32x2 oth, int wv) {
  u32x4 f;
  if (wv == 0) { f[0]=own[0]; f[1]=own[1]; f[2]=oth[0]; f[3]=oth[1]; }
  else         { f[0]=oth[0]; f[1]=oth[1]; f[2]=own[0]; f[3]=own[1]; }
  s16x8 r; __builtin_memcpy(&r, &f, 16);
  return r;
}

DEV f32x4 scl4(f32x4 v, float s) { f32x4 r; r[0]=v[0]*s; r[1]=v[1]*s; r[2]=v[2]*s; r[3]=v[3]*s; return r; }

// 2 waves per block: wave w owns output dims [16w, 16w+16). Each wave does
// half the MFMAs + half the activations; packed bf16 state halves are
// exchanged via LDS (8B/lane, partner = tid^64) once per phase.
__global__ __launch_bounds__(128, 1) void anima_kernel(Params P) {
  const int tid  = threadIdx.x;
  const int wv   = tid >> 6;
  const int lane = tid & 63;
  const int h = lane >> 4, c = lane & 15;
  const int bbase = blockIdx.x * 16;
  const int row = wv*16 + c;

  __shared__ unsigned long long xb[4][128];

  // ---- persistent weight fragments, own j-half only, scale pre-folded ----
  const float msc[15] = {N2L2E,N2L2E,N2L2E,  NL2E,NL2E,NL2E,  NL2E,NL2E,NL2E,
                         N2L2E,N2L2E,N2L2E,  N2L2E,N2L2E,N2L2E};
  s16x8 m[15];
#pragma unroll
  for (int i = 0; i < 15; ++i) m[i] = wfrag(P.mw[i], row, 32, 0, h, msc[i]);

  s16x8 g[4][2];   // att wmg img amg, k-chunks q=0,1
#pragma unroll
  for (int i = 0; i < 4; ++i)
#pragma unroll
    for (int q = 0; q < 2; ++q)
      g[i][q] = wfrag(P.gw[i], row, 64, 32*q, h, NL2E);

  s16x8 ef = zero8();          // encoder rows own-j, k 0..7 on h<2 lanes
  if (h < 2) { f32x4 v = ld4(P.enc_w + row*Sn + 4*h); ef = pk2s(v, zero4(), N2L2E); }

  s16x8 pf = (wv == 0 && c < 4) ? wfrag(P.phi_w, c, 32, 0, h, 1.0f) : zero8();

  const int o = wv*16 + 4*h;   // bias accum-init: outdim 16w+4h+r
  f32x4 bE  = scl4(ld4(P.enc_b + o), N2L2E);
  f32x4 bAt = scl4(ld4(P.gb[0] + o), NL2E);
  f32x4 bMu = scl4(ld4(P.gb[1] + o), NL2E);
  f32x4 bMI = scl4(ld4(P.gb[2] + o), NL2E);
  f32x4 bMA = scl4(ld4(P.gb[3] + o), NL2E);
  f32x4 bZ  = scl4(ld4(P.z_b + o),  NL2E);
  f32x4 bR  = scl4(ld4(P.r_b + o),  NL2E);
  f32x4 bH  = scl4(ld4(P.h_b + o),  N2L2E);
  f32x4 bA  = scl4(ld4(P.a_b + o),  N2L2E);
  f32x4 pb  = (wv == 0 && h == 0) ? ld4(P.phi_b) : zero4();

  // ---- state: I fp32 (own 4 dims), full bf16 fragments for W/I/A ----
  f32x4 iv = zero4();
  s16x8 Wf = zero8(), If = zero8(), Af = zero8();

  f32x4 ob = zero4();
  if (h < 2) ob = ld4(P.obs + (size_t)(bbase + c) * Sn + 4*h);

#pragma unroll 1
  for (int t = 0; t < Tn; ++t) {
    s16x8 Of = (h < 2) ? pk2s(ob, zero4(), 1.0f) : zero8();
    f32x4 nb = ob;
    if (h < 2 && t + 1 < Tn)
      nb = ld4(P.obs + ((size_t)(t+1)*Bn + bbase + c) * Sn + 4*h);

    // ---- phase A: W_all, att, wmg, enc (own j-half) ----
    f32x4 x = MF(m[0], Wf, zero4()); x = MF(m[1], If, x); f32x4 aWl = MF(m[2], Af, x); // -2L2E*Wall
    f32x4 y = MF(g[0][0], Wf, bAt);  f32x4 aAt = MF(g[0][1], If, y);                   // -L2E*attpre
    f32x4 u = MF(g[1][0], If, bMu);  f32x4 aMu = MF(g[1][1], Af, u);                   // -L2E*wmgpre
    f32x4 aE = MF(ef, Of, bE);                                                          // -2L2E*encpre
    f32x4 wn;
#pragma unroll
    for (int r = 0; r < 4; ++r) {
      float etp = fmaf(rcp_(1.f + ex2(aE[r])), -4.f*L2E, 2.f*L2E);  // -2L2E*tanh(enc)
      float at  = sg(aAt[r]);
      float mg  = sg(aMu[r]);
      float wp  = fmaf(etp, at, aWl[r]*mg);                          // -2L2E*Wn_pre
      wn[r] = th(wp);
    }
    u32x2 wn2 = pkx(wn);
    xb[0][tid] = pack64(wn2); __syncthreads();
    s16x8 Wnf = frag(wn2, unpack64(xb[0][tid ^ 64]), wv);

    // ---- phase B: z, r, mult_I ----
    x = MF(m[3], Wnf, bZ); x = MF(m[4], If, x); f32x4 aZ = MF(m[5], Af, x);
    y = MF(m[6], Wnf, bR); y = MF(m[7], If, y); f32x4 aR = MF(m[8], Af, y);
    u = MF(g[2][0], Wnf, bMI); f32x4 aMI = MF(g[2][1], Af, u);        // img over [W_new, A]
    f32x4 zz, ri, mi;
#pragma unroll
    for (int r = 0; r < 4; ++r) {
      zz[r] = sg(aZ[r]);
      ri[r] = sg(aR[r]) * iv[r];
      mi[r] = sg(aMI[r]);
    }
    u32x2 ri2 = pkx(ri);
    xb[1][tid] = pack64(ri2); __syncthreads();
    s16x8 rIf = frag(ri2, unpack64(xb[1][tid ^ 64]), wv);

    // ---- phase C: h, I_new ----
    x = MF(m[9], Wnf, bH); x = MF(m[10], rIf, x); f32x4 aH = MF(m[11], Af, x);
    f32x4 inw;
#pragma unroll
    for (int r = 0; r < 4; ++r) {
      float hv = th(aH[r]);
      float tt = hv * mi[r];
      inw[r] = fmaf(zz[r], tt - iv[r], iv[r]);   // (1-z)*iv + z*h*mi
    }
    u32x2 in2 = pkx(inw);
    xb[2][tid] = pack64(in2); __syncthreads();
    s16x8 Inf = frag(in2, unpack64(xb[2][tid ^ 64]), wv);

    // ---- phase D: A_all, mult_A, A_new ----
    x = MF(m[12], Wnf, bA); x = MF(m[13], Inf, x); f32x4 aAl = MF(m[14], Af, x);  // -2L2E*Aall
    y = MF(g[3][0], Wnf, bMA); f32x4 aMA = MF(g[3][1], Inf, y);                    // amg over [W_new, I_new]
    f32x4 an;
#pragma unroll
    for (int r = 0; r < 4; ++r) {
      float ma = sg(aMA[r]);
      an[r] = th(aAl[r] * ma);
    }
    u32x2 an2 = pkx(an);
    xb[3][tid] = pack64(an2); __syncthreads();
    s16x8 Anf = frag(an2, unpack64(xb[3][tid ^ 64]), wv);

    // ---- phase E: action = phi(A_new) + phi_b (wave0; h=0 lanes hold out[c][0..4)) ----
    if (wv == 0) {
      f32x4 aP = MF(pf, Anf, pb);
      if (h == 0)
        *(f32x4*)(P.out + ((size_t)t*Bn + bbase + c) * 4) = aP;
    }

    // ---- rotate state ----
    Wf = Wnf; If = Inf; Af = Anf; iv = inw; ob = nb;
  }
}

extern "C" void kernel_launch(void* const* d_in, const int* in_sizes, int n_in,
                              void* d_out, int out_size, void* d_ws, size_t ws_size,
                              hipStream_t stream) {
  (void)in_sizes; (void)n_in; (void)d_ws; (void)ws_size; (void)out_size;
  Params p;
  p.obs   = (const float*)d_in[0];
  p.enc_w = (const float*)d_in[1];
  p.enc_b = (const float*)d_in[2];
  for (int i = 0; i < 15; ++i) p.mw[i] = (const float*)d_in[3 + i];
  for (int i = 0; i < 4; ++i) {
    p.gw[i] = (const float*)d_in[18 + 2*i];
    p.gb[i] = (const float*)d_in[19 + 2*i];
  }
  p.z_b   = (const float*)d_in[26];
  p.r_b   = (const float*)d_in[27];
  p.h_b   = (const float*)d_in[28];
  p.a_b   = (const float*)d_in[29];
  p.phi_w = (const float*)d_in[30];
  p.phi_b = (const float*)d_in[31];
  p.out   = (float*)d_out;

  hipLaunchKernelGGL(anima_kernel, dim3(Bn / 16), dim3(128), 0, stream, p);
}